// Round 9
// baseline (254.226 us; speedup 1.0000x reference)
//
#include <hip/hip_runtime.h>

#define SEQ 2048
#define BATCH 2
#define DM 1024
#define NH 16
#define DH 64

typedef __bf16 bf16;
typedef __bf16 bf16x8 __attribute__((ext_vector_type(8)));
typedef __bf16 bf16x4 __attribute__((ext_vector_type(4)));
typedef float f32x4 __attribute__((ext_vector_type(4)));

#define MFMA16(a, b, c) __builtin_amdgcn_mfma_f32_16x16x32_bf16((a), (b), (c), 0, 0, 0)

#if __has_builtin(__builtin_amdgcn_exp2f)
#define EXP2(x) __builtin_amdgcn_exp2f(x)
#else
#define EXP2(x) exp2f(x)
#endif

// Q scale folds 1/sqrt(64) and log2(e) so softmax uses bare v_exp_f32 (exp2)
#define QSCALE 0.18033688f

// async global->LDS, 16B per lane; LDS dest = wave-uniform base + lane*16
typedef __attribute__((address_space(3))) void lds_void;
typedef __attribute__((address_space(1))) void glb_void;
__device__ __forceinline__ void gld16(void* lds, const void* g) {
    __builtin_amdgcn_global_load_lds((const glb_void*)g, (lds_void*)lds, 16, 0, 0);
}

// ---------------------------------------------------------------------------
// K0: fused prep. blocks [0,2048): cast x -> bf16. [2048,2816): transpose
// W_{Q,K,V} -> wT [p][he][k]. [2816,3072): transpose W_O -> woT [d][he].
// ---------------------------------------------------------------------------
__global__ __launch_bounds__(256) void k_prep(const float* __restrict__ x,
                                              const float* __restrict__ WQ,
                                              const float* __restrict__ WK,
                                              const float* __restrict__ WV,
                                              const float* __restrict__ WO,
                                              bf16* __restrict__ xb,
                                              bf16* __restrict__ wT,
                                              bf16* __restrict__ woT) {
    int bx = blockIdx.x;
    int t = threadIdx.x;
    if (bx < 2048) {
        int g = bx * 256 + t;
        const float4* x4 = (const float4*)x;
        float4 a = x4[2 * g];
        float4 b = x4[2 * g + 1];
        bf16x8 o;
        o[0] = (bf16)a.x; o[1] = (bf16)a.y; o[2] = (bf16)a.z; o[3] = (bf16)a.w;
        o[4] = (bf16)b.x; o[5] = (bf16)b.y; o[6] = (bf16)b.z; o[7] = (bf16)b.w;
        *(bf16x8*)(xb + 8 * g) = o;
        return;
    }
    __shared__ bf16 T[64 * 65];
    if (bx < 2816) {
        int id = bx - 2048;
        int kt = id & 15, ph = id >> 4;
        int p = ph >> 4, h = ph & 15;
        const float* Wp = (p == 0) ? WQ : (p == 1) ? WK : WV;
        const float* src = Wp + ((size_t)h * DM + (size_t)kt * 64) * DH;
        for (int i = 0; i < 4; i++) {
            int c = t + 256 * i;
            int r = c >> 4;
            int col = (c & 15) * 4;
            float4 v = *(const float4*)&src[r * 64 + col];
            T[(col + 0) * 65 + r] = (bf16)v.x;
            T[(col + 1) * 65 + r] = (bf16)v.y;
            T[(col + 2) * 65 + r] = (bf16)v.z;
            T[(col + 3) * 65 + r] = (bf16)v.w;
        }
        __syncthreads();
        bf16* dst = wT + (size_t)ph * 64 * DM + (size_t)kt * 64;
        for (int i = 0; i < 2; i++) {
            int c = t + 256 * i;
            int e = c >> 3;
            int k0 = (c & 7) * 8;
            bf16x8 o;
            for (int j = 0; j < 8; j++) o[j] = T[e * 65 + k0 + j];
            *(bf16x8*)&dst[(size_t)e * DM + k0] = o;
        }
    } else {
        int id = bx - 2816;
        int ht = id & 15, dt = id >> 4;
        for (int i = 0; i < 4; i++) {
            int c = t + 256 * i;
            int r = c >> 4;
            int col = (c & 15) * 4;
            float4 v = *(const float4*)&WO[((size_t)(ht * 64 + r)) * DM + dt * 64 + col];
            T[(col + 0) * 65 + r] = (bf16)v.x;
            T[(col + 1) * 65 + r] = (bf16)v.y;
            T[(col + 2) * 65 + r] = (bf16)v.z;
            T[(col + 3) * 65 + r] = (bf16)v.w;
        }
        __syncthreads();
        for (int i = 0; i < 2; i++) {
            int c = t + 256 * i;
            int d = c >> 3;
            int h0 = (c & 7) * 8;
            bf16x8 o;
            for (int j = 0; j < 8; j++) o[j] = T[d * 65 + h0 + j];
            *(bf16x8*)&woT[((size_t)(dt * 64 + d)) * DM + ht * 64 + h0] = o;
        }
    }
}

// ---------------------------------------------------------------------------
// K1: QKV projection — REGISTER-DIRECT GEMM (no LDS, no barriers). Both MFMA
// fragments are 16B-contiguous global runs (wT is [he][k] row-major), so each
// wave loads its 2 A-frags + 8 B-frags per 64-wide K-slab straight into VGPRs.
// Compiler pipelines across K-iters with fine-grained vmcnt (no vmcnt(0)
// barrier drain — the R8-measured stall). W-frags are wave-redundant but L1
// serves repeats; L2 headroom is ~12x. grid (32 mt, 8 nt, 3 p), 256 thr,
// 3 blocks/CU (single generation).
// ---------------------------------------------------------------------------
__global__ __launch_bounds__(256, 3) void k_qkv(const bf16* __restrict__ xb,
                                                const bf16* __restrict__ wT,
                                                const float* __restrict__ bQ,
                                                const float* __restrict__ bK,
                                                const float* __restrict__ bV,
                                                bf16* __restrict__ Qb,
                                                bf16* __restrict__ Kb,
                                                bf16* __restrict__ VTf) {
    int mt = blockIdx.x, nt = blockIdx.y, p = blockIdx.z;
    int t = threadIdx.x;
    int lane = t & 63, w = t >> 6;
    int l15 = lane & 15, quad = lane >> 4;

    const f32x4 z4 = {0.f, 0.f, 0.f, 0.f};
    f32x4 acc[2][8];
    for (int mi = 0; mi < 2; mi++)
        for (int ni = 0; ni < 8; ni++) acc[mi][ni] = z4;

    int m0 = mt * 128, n0 = nt * 128;
    int kl = quad * 8;   // this lane's k-offset within a 32-wide MFMA step
    const bf16* a0p = xb + (size_t)(m0 + w * 32 + l15) * DM + kl;
    const bf16* a1p = a0p + (size_t)16 * DM;
    const bf16* b0p = wT + ((size_t)p * 1024 + n0 + l15) * DM + kl;

    for (int k0 = 0; k0 < DM; k0 += 64) {
#pragma unroll
        for (int ks = 0; ks < 2; ks++) {
            int ko = k0 + ks * 32;
            bf16x8 a0 = *(const bf16x8*)(a0p + ko);
            bf16x8 a1 = *(const bf16x8*)(a1p + ko);
#pragma unroll
            for (int ni = 0; ni < 8; ni++) {
                bf16x8 bfr = *(const bf16x8*)(b0p + (size_t)(ni * 16) * DM + ko);
                acc[0][ni] = MFMA16(a0, bfr, acc[0][ni]);
                acc[1][ni] = MFMA16(a1, bfr, acc[1][ni]);
            }
        }
    }

    int b = mt >> 4;
    int kt = mt & 15;                 // 128-row tile within batch
    int s00 = kt * 128;
    if (p < 2) {
        const float* bias = (p == 0) ? bQ : bK;
        bf16* dst = (p == 0) ? Qb : Kb;
        float scale = (p == 0) ? QSCALE : 1.0f;
        for (int ni = 0; ni < 8; ni++) {
            int he = n0 + ni * 16 + l15;
            int h = he >> 6, e = he & 63;
            float bia = bias[he];
            size_t rb = (size_t)(b * NH + h) * SEQ * DH + e;
            for (int mi = 0; mi < 2; mi++)
                for (int r = 0; r < 4; r++) {
                    int s = s00 + w * 32 + mi * 16 + quad * 4 + r;
                    dst[rb + (size_t)s * DH] = (bf16)((acc[mi][ni][r] + bia) * scale);
                }
        }
    } else {
        // paired-fragment V store: frag = w*4 + no, slot (quad<<4)|l15,
        // element j = mi*4 + r <-> kv = w*32 + mi*16 + quad*4 + r
        for (int ni = 0; ni < 8; ni++) {
            int he = n0 + ni * 16 + l15;
            int h = he >> 6, e = he & 63;
            int no = (e >> 4) & 3;
            float bia = bV[he];
            size_t base = (((size_t)(b * NH + h) * 16 + kt) * 16 + (w * 4 + no)) * 512
                          + (size_t)((quad << 4) | l15) * 8;
            for (int mi = 0; mi < 2; mi++) {
                bf16x4 o;
                for (int r = 0; r < 4; r++) o[r] = (bf16)(acc[mi][ni][r] + bia);
                *(bf16x4*)&VTf[base + mi * 4] = o;
            }
        }
    }
}

// ---------------------------------------------------------------------------
// K2: flash attention. S^T = K(A) x Q(B); O = P(A) x V(B), P in registers.
// K double-buffered (staged during previous iter); V single-buffered, staged
// during the QK+softmax phase of the SAME iter. 48 KB LDS. All LDS reads are
// linear ds_read_b128. Block 512 thr = 8 waves x 16 q-rows.
// grid (32 bh, 16 y), qt = y<8?y:23-y (CU-paired blocks sum to 17 iters).
// ---------------------------------------------------------------------------
__global__ __launch_bounds__(512, 4) void k_attn(const bf16* __restrict__ Qb,
                                                 const bf16* __restrict__ Kb,
                                                 const bf16* __restrict__ VTf,
                                                 bf16* __restrict__ Zb) {
    int bh = blockIdx.x;
    int y = blockIdx.y;
    int qt = (y < 8) ? y : 23 - y;
    int h = bh & 15, b = bh >> 4;
    __shared__ __align__(16) bf16 Ks[2][16 * 512];   // 32 KB
    __shared__ __align__(16) bf16 Vs[16 * 512];      // 16 KB
    int t = threadIdx.x;
    int lane = t & 63, w = t >> 6;
    int l15 = lane & 15, quad = lane >> 4;

    const bf16* qbase = Qb + (size_t)bh * SEQ * DH;
    const bf16* kbase = Kb + (size_t)bh * SEQ * DH;
    const bf16* vfrag = VTf + (size_t)bh * 16 * 8192;

    int qr0 = qt * 128 + w * 16;
    bf16x8 aq[2];   // Q as B-operand: lane holds q=qr0+l15, e=ks*32+quad*8+j
    for (int ks = 0; ks < 2; ks++)
        aq[ks] = *(const bf16x8*)&qbase[(size_t)(qr0 + l15) * DH + ks * 32 + quad * 8];

    auto stageK = [&](int buf, int kt) {
        for (int i = 0; i < 2; i++) {
            int f = w * 2 + i;
            int ks = f >> 3, ni = f & 7;
            gld16(&Ks[buf][f * 512],
                  kbase + (size_t)(kt * 128 + ni * 16 + l15) * DH + ks * 32 + quad * 8);
        }
    };
    auto stageV = [&](int kt) {
        const bf16* vt = vfrag + (size_t)kt * 8192;
        for (int i = 0; i < 2; i++) {
            int f = w * 2 + i;
            gld16(&Vs[f * 512], vt + f * 512 + lane * 8);
        }
    };

    const bf16 one = (bf16)1.0f;
    const bf16x8 ones = {one, one, one, one, one, one, one, one};
    const f32x4 z4 = {0.f, 0.f, 0.f, 0.f};
    f32x4 acco[4], accd;
    for (int no = 0; no < 4; no++) acco[no] = z4;
    accd = z4;

    stageK(0, 0);

    for (int kt = 0; kt <= qt; kt++) {
        int buf = kt & 1;
        __syncthreads();   // K[kt] ready in Ks[buf]; Vs free (prev PV done)
        stageV(kt);        // V[kt] lands during QK+softmax below
        if (kt < qt) stageK(buf ^ 1, kt + 1);
        const bf16* Kbuf = Ks[buf];

        // S^T = K x Q^T : lane holds q=l15, kv=ni*16+quad*4+r
        f32x4 accs[8];
        for (int ni = 0; ni < 8; ni++) accs[ni] = z4;
        for (int ks = 0; ks < 2; ks++)
            for (int ni = 0; ni < 8; ni++) {
                bf16x8 ak = *(const bf16x8*)&Kbuf[(ks * 8 + ni) * 512 + lane * 8];
                accs[ni] = MFMA16(ak, aq[ks], accs[ni]);
            }

        if (kt == qt) {   // causal mask on diagonal tile
            int ql = w * 16 + l15;
            for (int ni = 0; ni < 8; ni++) {
                int kvl = ni * 16 + quad * 4;
                for (int r = 0; r < 4; r++)
                    if (kvl + r > ql) accs[ni][r] = -1e30f;
            }
        }

        // P^T = exp2(S^T) in registers
        bf16x4 pt[8];
        for (int ni = 0; ni < 8; ni++)
            for (int r = 0; r < 4; r++)
                pt[ni][r] = (bf16)EXP2(accs[ni][r]);

        __syncthreads();   // V[kt] (and K[kt+1]) landed

        // O += P(A) x V(B); V frags linear b128. ones-B -> per-lane denominator.
        for (int p4 = 0; p4 < 4; p4++) {
            bf16x8 ap;
            for (int j = 0; j < 4; j++) {
                ap[j] = pt[2 * p4][j];
                ap[4 + j] = pt[2 * p4 + 1][j];
            }
            accd = MFMA16(ap, ones, accd);
            for (int no = 0; no < 4; no++) {
                bf16x8 bv = *(const bf16x8*)&Vs[(p4 * 4 + no) * 512 + lane * 8];
                acco[no] = MFMA16(ap, bv, acco[no]);
            }
        }
    }

    // epilogue: O[q][e], per-lane denominator; 32B runs along e
    for (int r = 0; r < 4; r++) {
        float inv = 1.0f / accd[r];
        int q = qr0 + quad * 4 + r;
        size_t rowbase = ((size_t)b * SEQ + q) * DM + h * DH;
        for (int no = 0; no < 4; no++)
            Zb[rowbase + no * 16 + l15] = (bf16)(acco[no][r] * inv);
    }
}

// ---------------------------------------------------------------------------
// K3: out[s][d] = Zb(A, m=s, 128) @ woT(B, n=d, 64) + bO. Two-barrier 24KB
// single-buffer, grid (32, 16) = 512 blocks, 256 thr. 64-wide fp32 stores.
// ---------------------------------------------------------------------------
__global__ __launch_bounds__(256, 4) void k_out(const bf16* __restrict__ Zb,
                                                const bf16* __restrict__ woT,
                                                const float* __restrict__ bO,
                                                float* __restrict__ out) {
    int mt = blockIdx.x;
    int nt = blockIdx.y;
    __shared__ __align__(16) bf16 Xs[16 * 512];   // 16 KB (128 s-rows)
    __shared__ __align__(16) bf16 Ws[8 * 512];    //  8 KB (64 d-rows)
    int t = threadIdx.x;
    int lane = t & 63, w = t >> 6;
    int l15 = lane & 15, quad = lane >> 4;

    int m0 = mt * 128, n0 = nt * 64;
    const bf16* zrow = Zb + (size_t)m0 * DM;
    const bf16* wrow = woT + (size_t)n0 * DM;

    const f32x4 z4 = {0.f, 0.f, 0.f, 0.f};
    f32x4 acc[2][4];
    for (int mi = 0; mi < 2; mi++)
        for (int ni = 0; ni < 4; ni++) acc[mi][ni] = z4;

    for (int k0 = 0; k0 < DM; k0 += 64) {
        __syncthreads();
        for (int i = 0; i < 4; i++) {
            int f = w + 4 * i;
            int ks = f >> 3, ni = f & 7;
            gld16(Xs + f * 512,
                  zrow + (size_t)(ni * 16 + l15) * DM + k0 + ks * 32 + quad * 8);
        }
        for (int i = 0; i < 2; i++) {
            int f = w * 2 + i;
            int ks = f >> 2, ni = f & 3;
            gld16(Ws + f * 512,
                  wrow + (size_t)(ni * 16 + l15) * DM + k0 + ks * 32 + quad * 8);
        }
        __syncthreads();
        for (int ks = 0; ks < 2; ks++) {
            bf16x8 a0 = *(const bf16x8*)&Xs[(ks * 8 + w * 2 + 0) * 512 + lane * 8];
            bf16x8 a1 = *(const bf16x8*)&Xs[(ks * 8 + w * 2 + 1) * 512 + lane * 8];
            for (int ni = 0; ni < 4; ni++) {
                bf16x8 bfr = *(const bf16x8*)&Ws[(ks * 4 + ni) * 512 + lane * 8];
                acc[0][ni] = MFMA16(a0, bfr, acc[0][ni]);
                acc[1][ni] = MFMA16(a1, bfr, acc[1][ni]);
            }
        }
    }
    for (int ni = 0; ni < 4; ni++) {
        int d = n0 + ni * 16 + l15;
        float bia = bO[d];
        for (int mi = 0; mi < 2; mi++)
            for (int r = 0; r < 4; r++) {
                int s = m0 + w * 32 + mi * 16 + quad * 4 + r;
                out[(size_t)s * DM + d] = acc[mi][ni][r] + bia;
            }
    }
}

// ---------------------------------------------------------------------------
extern "C" void kernel_launch(void* const* d_in, const int* in_sizes, int n_in,
                              void* d_out, int out_size, void* d_ws, size_t ws_size,
                              hipStream_t stream) {
    const float* x  = (const float*)d_in[0];
    const float* WQ = (const float*)d_in[1];
    const float* WK = (const float*)d_in[2];
    const float* WV = (const float*)d_in[3];
    const float* WO = (const float*)d_in[4];
    const float* bQ = (const float*)d_in[5];
    const float* bK = (const float*)d_in[6];
    const float* bV = (const float*)d_in[7];
    const float* bO = (const float*)d_in[8];
    float* out = (float*)d_out;

    char* w = (char*)d_ws;
    bf16* xb    = (bf16*)(w + 0);                      //  8 MB [4096][1024]
    bf16* wqkvT = (bf16*)(w + (8u << 20));             //  6 MB [p][he][k]
    bf16* woT   = (bf16*)(w + (14u << 20));            //  2 MB [d][he]
    bf16* Qb    = (bf16*)(w + (16u << 20));            //  8 MB [b][h][s][e]
    bf16* Kb    = (bf16*)(w + (24u << 20));            //  8 MB [b][h][s][e]
    bf16* VTf   = (bf16*)(w + (32u << 20));            //  8 MB [bh][kt][16][512]
    bf16* Zb    = (bf16*)(w + (40u << 20));            //  8 MB [b][s][h*64+e]

    k_prep<<<3072, 256, 0, stream>>>(x, WQ, WK, WV, WO, xb, wqkvT, woT);
    k_qkv<<<dim3(32, 8, 3), 256, 0, stream>>>(xb, wqkvT, bQ, bK, bV, Qb, Kb, VTf);
    k_attn<<<dim3(32, 16), 512, 0, stream>>>(Qb, Kb, VTf, Zb);
    k_out<<<dim3(32, 16), 256, 0, stream>>>(Zb, woT, bO, out);
}

// Round 10
// 194.549 us; speedup vs baseline: 1.3067x; 1.3067x over previous
//
#include <hip/hip_runtime.h>

#define SEQ 2048
#define BATCH 2
#define DM 1024
#define NH 16
#define DH 64

typedef __bf16 bf16;
typedef __bf16 bf16x8 __attribute__((ext_vector_type(8)));
typedef __bf16 bf16x4 __attribute__((ext_vector_type(4)));
typedef float f32x4 __attribute__((ext_vector_type(4)));

#define MFMA16(a, b, c) __builtin_amdgcn_mfma_f32_16x16x32_bf16((a), (b), (c), 0, 0, 0)

#if __has_builtin(__builtin_amdgcn_exp2f)
#define EXP2(x) __builtin_amdgcn_exp2f(x)
#else
#define EXP2(x) exp2f(x)
#endif

// Q scale folds 1/sqrt(64) and log2(e) so softmax uses bare v_exp_f32 (exp2)
#define QSCALE 0.18033688f

// async global->LDS, 16B per lane; LDS dest = wave-uniform base + lane*16
typedef __attribute__((address_space(3))) void lds_void;
typedef __attribute__((address_space(1))) void glb_void;
__device__ __forceinline__ void gld16(void* lds, const void* g) {
    __builtin_amdgcn_global_load_lds((const glb_void*)g, (lds_void*)lds, 16, 0, 0);
}

// ---------------------------------------------------------------------------
// K0: fused prep. blocks [0,2048): cast x -> bf16. [2048,2816): transpose
// W_{Q,K,V} -> wT [p][he][k]. [2816,3072): transpose W_O -> woT [d][he].
// ---------------------------------------------------------------------------
__global__ __launch_bounds__(256) void k_prep(const float* __restrict__ x,
                                              const float* __restrict__ WQ,
                                              const float* __restrict__ WK,
                                              const float* __restrict__ WV,
                                              const float* __restrict__ WO,
                                              bf16* __restrict__ xb,
                                              bf16* __restrict__ wT,
                                              bf16* __restrict__ woT) {
    int bx = blockIdx.x;
    int t = threadIdx.x;
    if (bx < 2048) {
        int g = bx * 256 + t;
        const float4* x4 = (const float4*)x;
        float4 a = x4[2 * g];
        float4 b = x4[2 * g + 1];
        bf16x8 o;
        o[0] = (bf16)a.x; o[1] = (bf16)a.y; o[2] = (bf16)a.z; o[3] = (bf16)a.w;
        o[4] = (bf16)b.x; o[5] = (bf16)b.y; o[6] = (bf16)b.z; o[7] = (bf16)b.w;
        *(bf16x8*)(xb + 8 * g) = o;
        return;
    }
    __shared__ bf16 T[64 * 65];
    if (bx < 2816) {
        int id = bx - 2048;
        int kt = id & 15, ph = id >> 4;
        int p = ph >> 4, h = ph & 15;
        const float* Wp = (p == 0) ? WQ : (p == 1) ? WK : WV;
        const float* src = Wp + ((size_t)h * DM + (size_t)kt * 64) * DH;
        for (int i = 0; i < 4; i++) {
            int c = t + 256 * i;
            int r = c >> 4;
            int col = (c & 15) * 4;
            float4 v = *(const float4*)&src[r * 64 + col];
            T[(col + 0) * 65 + r] = (bf16)v.x;
            T[(col + 1) * 65 + r] = (bf16)v.y;
            T[(col + 2) * 65 + r] = (bf16)v.z;
            T[(col + 3) * 65 + r] = (bf16)v.w;
        }
        __syncthreads();
        bf16* dst = wT + (size_t)ph * 64 * DM + (size_t)kt * 64;
        for (int i = 0; i < 2; i++) {
            int c = t + 256 * i;
            int e = c >> 3;
            int k0 = (c & 7) * 8;
            bf16x8 o;
            for (int j = 0; j < 8; j++) o[j] = T[e * 65 + k0 + j];
            *(bf16x8*)&dst[(size_t)e * DM + k0] = o;
        }
    } else {
        int id = bx - 2816;
        int ht = id & 15, dt = id >> 4;
        for (int i = 0; i < 4; i++) {
            int c = t + 256 * i;
            int r = c >> 4;
            int col = (c & 15) * 4;
            float4 v = *(const float4*)&WO[((size_t)(ht * 64 + r)) * DM + dt * 64 + col];
            T[(col + 0) * 65 + r] = (bf16)v.x;
            T[(col + 1) * 65 + r] = (bf16)v.y;
            T[(col + 2) * 65 + r] = (bf16)v.z;
            T[(col + 3) * 65 + r] = (bf16)v.w;
        }
        __syncthreads();
        for (int i = 0; i < 2; i++) {
            int c = t + 256 * i;
            int d = c >> 3;
            int h0 = (c & 7) * 8;
            bf16x8 o;
            for (int j = 0; j < 8; j++) o[j] = T[d * 65 + h0 + j];
            *(bf16x8*)&woT[((size_t)(dt * 64 + d)) * DM + ht * 64 + h0] = o;
        }
    }
}

// ---------------------------------------------------------------------------
// K1: QKV projection. Reuse-split structure:
//   X (A-operand): ZERO cross-wave reuse -> register-direct with 1-iter
//     prefetch (parity-indexed regs). NOT R9: only the reuse-free operand
//     skips LDS, and it's prefetched with a full MFMA block of cover.
//   W (B-operand): read by all 4 waves -> LDS double-buffered, ONE barrier
//     per iter (k_attn-K pattern), 32 KB total (occupancy unchanged: 3/CU).
// Barriers per kernel: 16 (was 32), each drain overlapped with 16 MFMAs.
// grid (32 mt, 8 nt, 3 p), 256 thr. Epilogues unchanged (R8-verified).
// ---------------------------------------------------------------------------
__global__ __launch_bounds__(256, 3) void k_qkv(const bf16* __restrict__ xb,
                                                const bf16* __restrict__ wT,
                                                const float* __restrict__ bQ,
                                                const float* __restrict__ bK,
                                                const float* __restrict__ bV,
                                                bf16* __restrict__ Qb,
                                                bf16* __restrict__ Kb,
                                                bf16* __restrict__ VTf) {
    int mt = blockIdx.x, nt = blockIdx.y, p = blockIdx.z;
    __shared__ __align__(16) bf16 Ws[2][16 * 512];   // 32 KB dbuf
    int t = threadIdx.x;
    int lane = t & 63, w = t >> 6;
    int l15 = lane & 15, quad = lane >> 4;

    const f32x4 z4 = {0.f, 0.f, 0.f, 0.f};
    f32x4 acc[2][8];
    for (int mi = 0; mi < 2; mi++)
        for (int ni = 0; ni < 8; ni++) acc[mi][ni] = z4;

    int m0 = mt * 128, n0 = nt * 128;
    int kl = quad * 8;
    const bf16* a0p = xb + (size_t)(m0 + w * 32 + l15) * DM + kl;
    const bf16* a1p = a0p + (size_t)16 * DM;
    const bf16* wrow = wT + ((size_t)p * 1024 + n0) * DM;

    auto stageW = [&](int buf, int k0) {
#pragma unroll
        for (int i = 0; i < 4; i++) {
            int f = w + 4 * i;
            int ks = f >> 3, ni = f & 7;
            gld16(&Ws[buf][f * 512],
                  wrow + (size_t)(ni * 16 + l15) * DM + k0 + ks * 32 + quad * 8);
        }
    };

    bf16x8 xr[2][2][2];   // [parity][mi][ks]
    stageW(0, 0);
#pragma unroll
    for (int ks = 0; ks < 2; ks++) {
        xr[0][0][ks] = *(const bf16x8*)(a0p + ks * 32);
        xr[0][1][ks] = *(const bf16x8*)(a1p + ks * 32);
    }

#pragma unroll
    for (int it = 0; it < 16; it++) {
        int buf = it & 1;
        __syncthreads();   // W[it] ready in Ws[buf]; prev reads of buf^1 done
        if (it < 15) {
            int kn = (it + 1) * 64;
            stageW(buf ^ 1, kn);
#pragma unroll
            for (int ks = 0; ks < 2; ks++) {
                xr[buf ^ 1][0][ks] = *(const bf16x8*)(a0p + kn + ks * 32);
                xr[buf ^ 1][1][ks] = *(const bf16x8*)(a1p + kn + ks * 32);
            }
        }
#pragma unroll
        for (int ks = 0; ks < 2; ks++) {
#pragma unroll
            for (int ni = 0; ni < 8; ni++) {
                bf16x8 bfr = *(const bf16x8*)&Ws[buf][(ks * 8 + ni) * 512 + lane * 8];
                acc[0][ni] = MFMA16(xr[buf][0][ks], bfr, acc[0][ni]);
                acc[1][ni] = MFMA16(xr[buf][1][ks], bfr, acc[1][ni]);
            }
        }
    }

    int b = mt >> 4;
    int kt = mt & 15;                 // 128-row tile within batch
    int s00 = kt * 128;
    if (p < 2) {
        const float* bias = (p == 0) ? bQ : bK;
        bf16* dst = (p == 0) ? Qb : Kb;
        float scale = (p == 0) ? QSCALE : 1.0f;
        for (int ni = 0; ni < 8; ni++) {
            int he = n0 + ni * 16 + l15;
            int h = he >> 6, e = he & 63;
            float bia = bias[he];
            size_t rb = (size_t)(b * NH + h) * SEQ * DH + e;
            for (int mi = 0; mi < 2; mi++)
                for (int r = 0; r < 4; r++) {
                    int s = s00 + w * 32 + mi * 16 + quad * 4 + r;
                    dst[rb + (size_t)s * DH] = (bf16)((acc[mi][ni][r] + bia) * scale);
                }
        }
    } else {
        // paired-fragment V store: frag = w*4 + no, slot (quad<<4)|l15,
        // element j = mi*4 + r <-> kv = w*32 + mi*16 + quad*4 + r
        for (int ni = 0; ni < 8; ni++) {
            int he = n0 + ni * 16 + l15;
            int h = he >> 6, e = he & 63;
            int no = (e >> 4) & 3;
            float bia = bV[he];
            size_t base = (((size_t)(b * NH + h) * 16 + kt) * 16 + (w * 4 + no)) * 512
                          + (size_t)((quad << 4) | l15) * 8;
            for (int mi = 0; mi < 2; mi++) {
                bf16x4 o;
                for (int r = 0; r < 4; r++) o[r] = (bf16)(acc[mi][ni][r] + bia);
                *(bf16x4*)&VTf[base + mi * 4] = o;
            }
        }
    }
}

// ---------------------------------------------------------------------------
// K2: flash attention (R8-measured best, unchanged). S^T = K(A) x Q(B);
// O = P(A) x V(B), P in registers. K dbuf, V single-buf staged under QK.
// 48 KB LDS, all LDS reads linear ds_read_b128. Block 512 = 8 waves.
// grid (32 bh, 16 y), qt = y<8?y:23-y.
// ---------------------------------------------------------------------------
__global__ __launch_bounds__(512, 4) void k_attn(const bf16* __restrict__ Qb,
                                                 const bf16* __restrict__ Kb,
                                                 const bf16* __restrict__ VTf,
                                                 bf16* __restrict__ Zb) {
    int bh = blockIdx.x;
    int y = blockIdx.y;
    int qt = (y < 8) ? y : 23 - y;
    int h = bh & 15, b = bh >> 4;
    __shared__ __align__(16) bf16 Ks[2][16 * 512];   // 32 KB
    __shared__ __align__(16) bf16 Vs[16 * 512];      // 16 KB
    int t = threadIdx.x;
    int lane = t & 63, w = t >> 6;
    int l15 = lane & 15, quad = lane >> 4;

    const bf16* qbase = Qb + (size_t)bh * SEQ * DH;
    const bf16* kbase = Kb + (size_t)bh * SEQ * DH;
    const bf16* vfrag = VTf + (size_t)bh * 16 * 8192;

    int qr0 = qt * 128 + w * 16;
    bf16x8 aq[2];   // Q as B-operand: lane holds q=qr0+l15, e=ks*32+quad*8+j
    for (int ks = 0; ks < 2; ks++)
        aq[ks] = *(const bf16x8*)&qbase[(size_t)(qr0 + l15) * DH + ks * 32 + quad * 8];

    auto stageK = [&](int buf, int kt) {
        for (int i = 0; i < 2; i++) {
            int f = w * 2 + i;
            int ks = f >> 3, ni = f & 7;
            gld16(&Ks[buf][f * 512],
                  kbase + (size_t)(kt * 128 + ni * 16 + l15) * DH + ks * 32 + quad * 8);
        }
    };
    auto stageV = [&](int kt) {
        const bf16* vt = vfrag + (size_t)kt * 8192;
        for (int i = 0; i < 2; i++) {
            int f = w * 2 + i;
            gld16(&Vs[f * 512], vt + f * 512 + lane * 8);
        }
    };

    const bf16 one = (bf16)1.0f;
    const bf16x8 ones = {one, one, one, one, one, one, one, one};
    const f32x4 z4 = {0.f, 0.f, 0.f, 0.f};
    f32x4 acco[4], accd;
    for (int no = 0; no < 4; no++) acco[no] = z4;
    accd = z4;

    stageK(0, 0);

    for (int kt = 0; kt <= qt; kt++) {
        int buf = kt & 1;
        __syncthreads();   // K[kt] ready in Ks[buf]; Vs free (prev PV done)
        stageV(kt);        // V[kt] lands during QK+softmax below
        if (kt < qt) stageK(buf ^ 1, kt + 1);
        const bf16* Kbuf = Ks[buf];

        // S^T = K x Q^T : lane holds q=l15, kv=ni*16+quad*4+r
        f32x4 accs[8];
        for (int ni = 0; ni < 8; ni++) accs[ni] = z4;
        for (int ks = 0; ks < 2; ks++)
            for (int ni = 0; ni < 8; ni++) {
                bf16x8 ak = *(const bf16x8*)&Kbuf[(ks * 8 + ni) * 512 + lane * 8];
                accs[ni] = MFMA16(ak, aq[ks], accs[ni]);
            }

        if (kt == qt) {   // causal mask on diagonal tile
            int ql = w * 16 + l15;
            for (int ni = 0; ni < 8; ni++) {
                int kvl = ni * 16 + quad * 4;
                for (int r = 0; r < 4; r++)
                    if (kvl + r > ql) accs[ni][r] = -1e30f;
            }
        }

        // P^T = exp2(S^T) in registers
        bf16x4 pt[8];
        for (int ni = 0; ni < 8; ni++)
            for (int r = 0; r < 4; r++)
                pt[ni][r] = (bf16)EXP2(accs[ni][r]);

        __syncthreads();   // V[kt] (and K[kt+1]) landed

        // O += P(A) x V(B); V frags linear b128. ones-B -> per-lane denominator.
        for (int p4 = 0; p4 < 4; p4++) {
            bf16x8 ap;
            for (int j = 0; j < 4; j++) {
                ap[j] = pt[2 * p4][j];
                ap[4 + j] = pt[2 * p4 + 1][j];
            }
            accd = MFMA16(ap, ones, accd);
            for (int no = 0; no < 4; no++) {
                bf16x8 bv = *(const bf16x8*)&Vs[(p4 * 4 + no) * 512 + lane * 8];
                acco[no] = MFMA16(ap, bv, acco[no]);
            }
        }
    }

    // epilogue: O[q][e], per-lane denominator; 32B runs along e
    for (int r = 0; r < 4; r++) {
        float inv = 1.0f / accd[r];
        int q = qr0 + quad * 4 + r;
        size_t rowbase = ((size_t)b * SEQ + q) * DM + h * DH;
        for (int no = 0; no < 4; no++)
            Zb[rowbase + no * 16 + l15] = (bf16)(acco[no][r] * inv);
    }
}

// ---------------------------------------------------------------------------
// K3: out[s][d] = Zb(A, m=s, 128) @ woT(B, n=d, 64) + bO. Reuse-split like
// k_qkv: Zb register-direct prefetch (no cross-wave reuse), woT dbuf in LDS
// (16 KB), ONE barrier/iter. grid (32, 16) = 512 blocks. 64-wide fp32 stores.
// ---------------------------------------------------------------------------
__global__ __launch_bounds__(256, 4) void k_out(const bf16* __restrict__ Zb,
                                                const bf16* __restrict__ woT,
                                                const float* __restrict__ bO,
                                                float* __restrict__ out) {
    int mt = blockIdx.x;
    int nt = blockIdx.y;
    __shared__ __align__(16) bf16 Ws[2][8 * 512];   // 16 KB dbuf (64 d-rows)
    int t = threadIdx.x;
    int lane = t & 63, w = t >> 6;
    int l15 = lane & 15, quad = lane >> 4;

    int m0 = mt * 128, n0 = nt * 64;
    int kl = quad * 8;
    const bf16* a0p = Zb + (size_t)(m0 + w * 32 + l15) * DM + kl;
    const bf16* a1p = a0p + (size_t)16 * DM;
    const bf16* wrow = woT + (size_t)n0 * DM;

    const f32x4 z4 = {0.f, 0.f, 0.f, 0.f};
    f32x4 acc[2][4];
    for (int mi = 0; mi < 2; mi++)
        for (int ni = 0; ni < 4; ni++) acc[mi][ni] = z4;

    auto stageW = [&](int buf, int k0) {
#pragma unroll
        for (int i = 0; i < 2; i++) {
            int f = w * 2 + i;
            int ks = f >> 2, ni = f & 3;
            gld16(&Ws[buf][f * 512],
                  wrow + (size_t)(ni * 16 + l15) * DM + k0 + ks * 32 + quad * 8);
        }
    };

    bf16x8 xr[2][2][2];   // [parity][mi][ks]
    stageW(0, 0);
#pragma unroll
    for (int ks = 0; ks < 2; ks++) {
        xr[0][0][ks] = *(const bf16x8*)(a0p + ks * 32);
        xr[0][1][ks] = *(const bf16x8*)(a1p + ks * 32);
    }

#pragma unroll
    for (int it = 0; it < 16; it++) {
        int buf = it & 1;
        __syncthreads();
        if (it < 15) {
            int kn = (it + 1) * 64;
            stageW(buf ^ 1, kn);
#pragma unroll
            for (int ks = 0; ks < 2; ks++) {
                xr[buf ^ 1][0][ks] = *(const bf16x8*)(a0p + kn + ks * 32);
                xr[buf ^ 1][1][ks] = *(const bf16x8*)(a1p + kn + ks * 32);
            }
        }
#pragma unroll
        for (int ks = 0; ks < 2; ks++) {
#pragma unroll
            for (int ni = 0; ni < 4; ni++) {
                bf16x8 bfr = *(const bf16x8*)&Ws[buf][(ks * 4 + ni) * 512 + lane * 8];
                acc[0][ni] = MFMA16(xr[buf][0][ks], bfr, acc[0][ni]);
                acc[1][ni] = MFMA16(xr[buf][1][ks], bfr, acc[1][ni]);
            }
        }
    }
    for (int ni = 0; ni < 4; ni++) {
        int d = n0 + ni * 16 + l15;
        float bia = bO[d];
        for (int mi = 0; mi < 2; mi++)
            for (int r = 0; r < 4; r++) {
                int s = m0 + w * 32 + mi * 16 + quad * 4 + r;
                out[(size_t)s * DM + d] = acc[mi][ni][r] + bia;
            }
    }
}

// ---------------------------------------------------------------------------
extern "C" void kernel_launch(void* const* d_in, const int* in_sizes, int n_in,
                              void* d_out, int out_size, void* d_ws, size_t ws_size,
                              hipStream_t stream) {
    const float* x  = (const float*)d_in[0];
    const float* WQ = (const float*)d_in[1];
    const float* WK = (const float*)d_in[2];
    const float* WV = (const float*)d_in[3];
    const float* WO = (const float*)d_in[4];
    const float* bQ = (const float*)d_in[5];
    const float* bK = (const float*)d_in[6];
    const float* bV = (const float*)d_in[7];
    const float* bO = (const float*)d_in[8];
    float* out = (float*)d_out;

    char* w = (char*)d_ws;
    bf16* xb    = (bf16*)(w + 0);                      //  8 MB [4096][1024]
    bf16* wqkvT = (bf16*)(w + (8u << 20));             //  6 MB [p][he][k]
    bf16* woT   = (bf16*)(w + (14u << 20));            //  2 MB [d][he]
    bf16* Qb    = (bf16*)(w + (16u << 20));            //  8 MB [b][h][s][e]
    bf16* Kb    = (bf16*)(w + (24u << 20));            //  8 MB [b][h][s][e]
    bf16* VTf   = (bf16*)(w + (32u << 20));            //  8 MB [bh][kt][16][512]
    bf16* Zb    = (bf16*)(w + (40u << 20));            //  8 MB [b][s][h*64+e]

    k_prep<<<3072, 256, 0, stream>>>(x, WQ, WK, WV, WO, xb, wqkvT, woT);
    k_qkv<<<dim3(32, 8, 3), 256, 0, stream>>>(xb, wqkvT, bQ, bK, bV, Qb, Kb, VTf);
    k_attn<<<dim3(32, 16), 512, 0, stream>>>(Qb, Kb, VTf, Zb);
    k_out<<<dim3(32, 16), 256, 0, stream>>>(Zb, woT, bO, out);
}